// Round 6
// baseline (434.666 us; speedup 1.0000x reference)
//
#include <hip/hip_runtime.h>

typedef float v2f __attribute__((ext_vector_type(2)));

#define T_LEN 2048
#define BB    128
#define CC    128
#define EE    32
#define HH    64
#define PRED  336
#define CH    16          // steps per ring chunk
#define NCH   21          // 21*16 = 336

#define PADT(t) ((t) + ((t) >> 7))   // +1 float per 128 -> breaks stride-128 bank aliasing

__device__ __forceinline__ v2f mk2(float a, float b) { v2f t; t.x = a; t.y = b; return t; }
__device__ __forceinline__ float rl(float v, int j) {
    return __int_as_float(__builtin_amdgcn_readlane(__float_as_int(v), j));
}

// ---------------------------------------------------------------------------
// ONE kernel, one block (256 thr = 4 waves) per batch element.
//
// Prologue (all waves): channel-0 extract, 7-tap edge-clamped moving average,
// 4 encoder tanh-GEMVs -> s_v[32].  Each wave then builds its per-lane
// columns of the u-space constant matrices in registers:
//   producer: M_ag = W_o@[W_in|W_g]  (v2f[64]);  consumers: M_r = W_o@Wr.
//
// Scan (u-space linear recurrence; logmap0(expmap0(v)) == v):
//   wave 0 (producer): u_h = silu(A_h)*sigm(G_h);  AG += u@M_ag + c_ag.
//     The gather of u across lanes uses v_readlane (register crossbar,
//     compile-time lane index -> SGPR FMA operand): NO LDS, NO waitcnt on
//     the serial chain.  u is also posted to the LDS ring (fire-and-forget).
//   waves 1,2 (consumers): P_c += u@M_r[:,c] + c_r;  store P (= pred_n).
//     Chunked double-buffered ring, one barrier per 16 steps.
//   wave 3: barrier companion only.
// ---------------------------------------------------------------------------
__global__ __launch_bounds__(256, 1) void fused_kernel(
    const float* __restrict__ x,
    const float* __restrict__ WeT,  const float* __restrict__ beT,
    const float* __restrict__ WeW,  const float* __restrict__ beW,
    const float* __restrict__ WeD,  const float* __restrict__ beD,
    const float* __restrict__ WeR,  const float* __restrict__ beR,
    const float* __restrict__ Wdin, const float* __restrict__ bdin,
    const float* __restrict__ Wdg,  const float* __restrict__ bdg,
    const float* __restrict__ Wdo,  const float* __restrict__ bdo,
    const float* __restrict__ Wr,   const float* __restrict__ br,
    float* __restrict__ out)
{
    __shared__ __align__(16) float s_x   [T_LEN + 6];
    __shared__ __align__(16) float s_tr  [T_LEN + 16];   // padded via PADT
    __shared__ __align__(16) float s_rs  [T_LEN + 16];
    __shared__ __align__(16) float s_part[4][32][32];
    __shared__ __align__(16) float s_red [4][32];
    __shared__ __align__(16) float s_v   [EE];
    __shared__ __align__(16) float s_u   [2][CH][HH];    // 8 KB ring

    const int tid  = threadIdx.x;
    const int wid  = tid >> 6;
    const int lane = tid & 63;
    const int b    = blockIdx.x;
    const float* xb = x + (size_t)b * T_LEN * CC;

    // ---- channel-0 with halo, edge-clamped
    for (int i = tid; i < T_LEN + 6; i += 256) {
        int t = i - 3;
        t = t < 0 ? 0 : (t > T_LEN - 1 ? T_LEN - 1 : t);
        s_x[i] = xb[(size_t)t * CC];
    }
    __syncthreads();

    // ---- 7-tap moving average (s_x index t+3 == global t)
    for (int t = tid; t < T_LEN; t += 256) {
        float s = 0.f;
        #pragma unroll
        for (int j = 0; j < 7; ++j) s += s_x[t + j];
        float tm = s * (1.0f / 7.0f);
        s_tr[PADT(t)] = tm;
        s_rs[PADT(t)] = s_x[t + 3] - tm;
    }
    __syncthreads();

    // ---- 4 encoder GEMV partials: thread = (e-quad eq, t-group tg of 32)
    {
        const int eq = tid & 7, tg = tid >> 3;      // eq: e/4, tg: 0..31
        float4 aT = {0,0,0,0}, aW = aT, aD = aT, aR = aT;
        const float4* WT4 = (const float4*)WeT;
        const float4* WW4 = (const float4*)WeW;
        const float4* WD4 = (const float4*)WeD;
        const float4* WR4 = (const float4*)WeR;
        #pragma unroll 4
        for (int j = 0; j < 64; ++j) {
            int t  = tg * 64 + j;
            int wi = t * 8 + eq;
            float trv = s_tr[PADT(t)], rsv = s_rs[PADT(t)];
            float4 w;
            w = WT4[wi]; aT.x += trv*w.x; aT.y += trv*w.y; aT.z += trv*w.z; aT.w += trv*w.w;
            w = WW4[wi]; aW.x += rsv*w.x; aW.y += rsv*w.y; aW.z += rsv*w.z; aW.w += rsv*w.w;
            w = WD4[wi]; aD.x += rsv*w.x; aD.y += rsv*w.y; aD.z += rsv*w.z; aD.w += rsv*w.w;
            w = WR4[wi]; aR.x += rsv*w.x; aR.y += rsv*w.y; aR.z += rsv*w.z; aR.w += rsv*w.w;
        }
        ((float4*)&s_part[0][tg][0])[eq] = aT;
        ((float4*)&s_part[1][tg][0])[eq] = aW;
        ((float4*)&s_part[2][tg][0])[eq] = aD;
        ((float4*)&s_part[3][tg][0])[eq] = aR;
    }
    __syncthreads();

    if (tid < 128) {                // reduce 32 t-groups per (matrix, e)
        const int m = tid >> 5, e = tid & 31;
        float s = 0.f;
        #pragma unroll
        for (int g = 0; g < 32; ++g) s += s_part[m][g][e];
        s_red[m][e] = s;
    }
    __syncthreads();

    if (tid < EE) {
        s_v[tid] = tanhf(s_red[0][tid] + beT[tid])
                 + tanhf(s_red[1][tid] + beW[tid])
                 + tanhf(s_red[2][tid] + beD[tid])
                 + tanhf(s_red[3][tid] + beR[tid]);
    }
    __syncthreads();

    if (wid == 0) {
        // ================= producer: A,G state for h = lane =================
        v2f wig[EE];                      // {W_in[e][lane], W_g[e][lane]}
        #pragma unroll
        for (int e = 0; e < EE; ++e)
            wig[e] = mk2(Wdin[e * HH + lane], Wdg[e * HH + lane]);

        v2f m_ag[HH];                     // column j of W_o@[W_in|W_g]
        #pragma unroll 2
        for (int k = 0; k < HH; ++k) {
            v2f m = mk2(0.f, 0.f);
            #pragma unroll
            for (int e = 0; e < EE; ++e) m += Wdo[k * EE + e] * wig[e];
            m_ag[k] = m;
        }
        v2f c_ag = mk2(0.f, 0.f);
        v2f ag   = mk2(bdin[lane], bdg[lane]);
        #pragma unroll
        for (int e = 0; e < EE; ++e) {
            c_ag += bdo[e] * wig[e];
            ag   += s_v[e] * wig[e];
        }

        for (int c = 0; c <= NCH; ++c) {
            if (c < NCH) {
                float* ring = &s_u[c & 1][0][0];
                for (int i = 0; i < CH; ++i) {
                    float a = ag.x, g = ag.y;
                    float u = a * __builtin_amdgcn_rcpf(
                        (1.f + __expf(-a)) * (1.f + __expf(-g)));
                    ring[i * HH + lane] = u;      // posted; not on serial path

                    // register-crossbar gather: readlane -> SGPR FMA operand
                    v2f acc0 = c_ag, acc1 = mk2(0.f, 0.f),
                        acc2 = acc1, acc3 = acc1;
                    #pragma unroll
                    for (int j = 0; j < HH; j += 4) {
                        acc0 += rl(u, j    ) * m_ag[j    ];
                        acc1 += rl(u, j + 1) * m_ag[j + 1];
                        acc2 += rl(u, j + 2) * m_ag[j + 2];
                        acc3 += rl(u, j + 3) * m_ag[j + 3];
                    }
                    ag += (acc0 + acc1) + (acc2 + acc3);
                }
            }
            __syncthreads();
        }
    } else if (wid <= 2) {
        // ============ consumer: P state (pred) for channel c0 ===============
        const int c0 = (wid - 1) * 64 + lane;
        float wr[EE];
        #pragma unroll
        for (int e = 0; e < EE; ++e) wr[e] = Wr[e * CC + c0];

        float m_r[HH];                    // column j of W_o@Wr for channel c0
        #pragma unroll 2
        for (int k = 0; k < HH; ++k) {
            float m = 0.f;
            #pragma unroll
            for (int e = 0; e < EE; ++e) m += Wdo[k * EE + e] * wr[e];
            m_r[k] = m;
        }
        float c_r = 0.f, P = br[c0];
        #pragma unroll
        for (int e = 0; e < EE; ++e) {
            c_r += bdo[e] * wr[e];
            P   += s_v[e] * wr[e];        // P_{-1} = tv0@Wr + br
        }

        float* outb = out + (size_t)b * PRED * CC + c0;

        for (int c = 0; c <= NCH; ++c) {
            if (c > 0) {
                const float* ring = &s_u[(c - 1) & 1][0][0];
                const int n0 = (c - 1) * CH;
                for (int i = 0; i < CH; ++i) {
                    float a0 = c_r, a1 = 0.f, a2 = 0.f, a3 = 0.f;
                    const float4* u4 = (const float4*)(ring + i * HH);
                    #pragma unroll
                    for (int k = 0; k < HH / 4; ++k) {
                        float4 q = u4[k];
                        a0 += q.x * m_r[4 * k    ];
                        a1 += q.y * m_r[4 * k + 1];
                        a2 += q.z * m_r[4 * k + 2];
                        a3 += q.w * m_r[4 * k + 3];
                    }
                    P += (a0 + a1) + (a2 + a3);
                    outb[(size_t)(n0 + i) * CC] = P;
                }
            }
            __syncthreads();
        }
    } else {
        // ================= wave 3: barrier companion =======================
        for (int c = 0; c <= NCH; ++c) __syncthreads();
    }
}

extern "C" void kernel_launch(void* const* d_in, const int* in_sizes, int n_in,
                              void* d_out, int out_size, void* d_ws, size_t ws_size,
                              hipStream_t stream)
{
    const float* x    = (const float*)d_in[0];
    const float* WeT  = (const float*)d_in[1];
    const float* beT  = (const float*)d_in[2];
    const float* WeW  = (const float*)d_in[3];
    const float* beW  = (const float*)d_in[4];
    const float* WeD  = (const float*)d_in[5];
    const float* beD  = (const float*)d_in[6];
    const float* WeR  = (const float*)d_in[7];
    const float* beR  = (const float*)d_in[8];
    const float* Wdin = (const float*)d_in[9];
    const float* bdin = (const float*)d_in[10];
    const float* Wdg  = (const float*)d_in[11];
    const float* bdg  = (const float*)d_in[12];
    const float* Wdo  = (const float*)d_in[13];
    const float* bdo  = (const float*)d_in[14];
    const float* Wr   = (const float*)d_in[15];
    const float* br   = (const float*)d_in[16];

    fused_kernel<<<BB, 256, 0, stream>>>(x, WeT, beT, WeW, beW, WeD, beD,
                                         WeR, beR, Wdin, bdin, Wdg, bdg,
                                         Wdo, bdo, Wr, br, (float*)d_out);
}

// Round 7
// 408.901 us; speedup vs baseline: 1.0630x; 1.0630x over previous
//
#include <hip/hip_runtime.h>

typedef float v2f __attribute__((ext_vector_type(2)));

#define T_LEN 2048
#define BB    128
#define CC    128
#define EE    32
#define HH    64
#define PRED  336
#define CH    16          // steps per ring chunk
#define NCH   21          // 21*16 = 336

#define PADT(t) ((t) + ((t) >> 7))

__device__ __forceinline__ v2f mk2(float a, float b) { v2f t; t.x = a; t.y = b; return t; }
__device__ __forceinline__ float rl(float v, int j) {
    return __int_as_float(__builtin_amdgcn_readlane(__float_as_int(v), j));
}

// ---------------------------------------------------------------------------
// ONE kernel, one block (256 thr = 4 waves) per batch element.
// Prologue: channel-0 extract, 7-tap MA, 4 encoder tanh-GEMVs -> s_v[32];
// each wave builds its columns of the u-space constant matrices IN REGISTERS
// (all build loops FULLY unrolled -> constant indices -> no scratch demotion;
//  R5/R6 regressed because `#pragma unroll 2` forced M into scratch).
// Scan (u-space linear recurrence; logmap0(expmap0(v)) == v):
//   wave 0: u_h = silu(A_h)*sigm(G_h);  AG += u@M_ag + c_ag via v_readlane
//           (register crossbar, zero LDS on the serial chain); u posted to
//           the LDS ring (fire-and-forget).
//   waves 1,2: P_c += u@M_r[:,c] + c_r; store P. Double-buffered ring,
//           one barrier per 16 steps.  wave 3: barrier companion.
// ---------------------------------------------------------------------------
__global__ __launch_bounds__(256, 1) void fused_kernel(
    const float* __restrict__ x,
    const float* __restrict__ WeT,  const float* __restrict__ beT,
    const float* __restrict__ WeW,  const float* __restrict__ beW,
    const float* __restrict__ WeD,  const float* __restrict__ beD,
    const float* __restrict__ WeR,  const float* __restrict__ beR,
    const float* __restrict__ Wdin, const float* __restrict__ bdin,
    const float* __restrict__ Wdg,  const float* __restrict__ bdg,
    const float* __restrict__ Wdo,  const float* __restrict__ bdo,
    const float* __restrict__ Wr,   const float* __restrict__ br,
    float* __restrict__ out)
{
    __shared__ __align__(16) float s_x   [T_LEN + 6];
    __shared__ __align__(16) float s_tr  [T_LEN + 16];
    __shared__ __align__(16) float s_rs  [T_LEN + 16];
    __shared__ __align__(16) float s_part[4][32][32];
    __shared__ __align__(16) float s_red [4][32];
    __shared__ __align__(16) float s_v   [EE];
    __shared__ __align__(16) float s_u   [2][CH][HH];    // 8 KB ring

    const int tid  = threadIdx.x;
    const int wid  = tid >> 6;
    const int lane = tid & 63;
    const int b    = blockIdx.x;
    const float* xb = x + (size_t)b * T_LEN * CC;

    // ---- channel-0 with halo, edge-clamped
    for (int i = tid; i < T_LEN + 6; i += 256) {
        int t = i - 3;
        t = t < 0 ? 0 : (t > T_LEN - 1 ? T_LEN - 1 : t);
        s_x[i] = xb[(size_t)t * CC];
    }
    __syncthreads();

    // ---- 7-tap moving average (s_x index t+3 == global t)
    for (int t = tid; t < T_LEN; t += 256) {
        float s = 0.f;
        #pragma unroll
        for (int j = 0; j < 7; ++j) s += s_x[t + j];
        float tm = s * (1.0f / 7.0f);
        s_tr[PADT(t)] = tm;
        s_rs[PADT(t)] = s_x[t + 3] - tm;
    }
    __syncthreads();

    // ---- 4 encoder GEMV partials: thread = (e-quad eq, t-group tg of 32)
    {
        const int eq = tid & 7, tg = tid >> 3;
        float4 aT = {0,0,0,0}, aW = aT, aD = aT, aR = aT;
        const float4* WT4 = (const float4*)WeT;
        const float4* WW4 = (const float4*)WeW;
        const float4* WD4 = (const float4*)WeD;
        const float4* WR4 = (const float4*)WeR;
        #pragma unroll 4
        for (int j = 0; j < 64; ++j) {
            int t  = tg * 64 + j;
            int wi = t * 8 + eq;
            float trv = s_tr[PADT(t)], rsv = s_rs[PADT(t)];
            float4 w;
            w = WT4[wi]; aT.x += trv*w.x; aT.y += trv*w.y; aT.z += trv*w.z; aT.w += trv*w.w;
            w = WW4[wi]; aW.x += rsv*w.x; aW.y += rsv*w.y; aW.z += rsv*w.z; aW.w += rsv*w.w;
            w = WD4[wi]; aD.x += rsv*w.x; aD.y += rsv*w.y; aD.z += rsv*w.z; aD.w += rsv*w.w;
            w = WR4[wi]; aR.x += rsv*w.x; aR.y += rsv*w.y; aR.z += rsv*w.z; aR.w += rsv*w.w;
        }
        ((float4*)&s_part[0][tg][0])[eq] = aT;
        ((float4*)&s_part[1][tg][0])[eq] = aW;
        ((float4*)&s_part[2][tg][0])[eq] = aD;
        ((float4*)&s_part[3][tg][0])[eq] = aR;
    }
    __syncthreads();

    if (tid < 128) {
        const int m = tid >> 5, e = tid & 31;
        float s = 0.f;
        #pragma unroll
        for (int g = 0; g < 32; ++g) s += s_part[m][g][e];
        s_red[m][e] = s;
    }
    __syncthreads();

    if (tid < EE) {
        s_v[tid] = tanhf(s_red[0][tid] + beT[tid])
                 + tanhf(s_red[1][tid] + beW[tid])
                 + tanhf(s_red[2][tid] + beD[tid])
                 + tanhf(s_red[3][tid] + beR[tid]);
    }
    __syncthreads();

    if (wid == 0) {
        // ================= producer: A,G state for h = lane =================
        v2f wig[EE];
        #pragma unroll
        for (int e = 0; e < EE; ++e)
            wig[e] = mk2(Wdin[e * HH + lane], Wdg[e * HH + lane]);

        // M_ag columns — FULL unroll, constant indices => stays in VGPRs
        v2f m_ag[HH];
        #pragma unroll
        for (int k = 0; k < HH; ++k) {
            v2f m = mk2(0.f, 0.f);
            #pragma unroll
            for (int e = 0; e < EE; ++e) m += Wdo[k * EE + e] * wig[e];
            m_ag[k] = m;
        }
        v2f c_ag = mk2(0.f, 0.f);
        v2f ag   = mk2(bdin[lane], bdg[lane]);
        #pragma unroll
        for (int e = 0; e < EE; ++e) {
            c_ag += bdo[e] * wig[e];
            ag   += s_v[e] * wig[e];
        }

        for (int c = 0; c <= NCH; ++c) {
            if (c < NCH) {
                float* ring = &s_u[c & 1][0][0];
                for (int i = 0; i < CH; ++i) {
                    float a = ag.x, g = ag.y;
                    float u = a * __builtin_amdgcn_rcpf(
                        (1.f + __expf(-a)) * (1.f + __expf(-g)));
                    ring[i * HH + lane] = u;      // posted; off the serial path

                    v2f acc0 = c_ag, acc1 = mk2(0.f, 0.f),
                        acc2 = acc1, acc3 = acc1;
                    #pragma unroll
                    for (int j = 0; j < HH; j += 4) {
                        acc0 += rl(u, j    ) * m_ag[j    ];
                        acc1 += rl(u, j + 1) * m_ag[j + 1];
                        acc2 += rl(u, j + 2) * m_ag[j + 2];
                        acc3 += rl(u, j + 3) * m_ag[j + 3];
                    }
                    ag += (acc0 + acc1) + (acc2 + acc3);
                }
            }
            __syncthreads();
        }
    } else if (wid <= 2) {
        // ============ consumer: P state (pred) for channel c0 ===============
        const int c0 = (wid - 1) * 64 + lane;
        float wr[EE];
        #pragma unroll
        for (int e = 0; e < EE; ++e) wr[e] = Wr[e * CC + c0];

        float m_r[HH];                    // FULL unroll => registers
        #pragma unroll
        for (int k = 0; k < HH; ++k) {
            float m = 0.f;
            #pragma unroll
            for (int e = 0; e < EE; ++e) m += Wdo[k * EE + e] * wr[e];
            m_r[k] = m;
        }
        float c_r = 0.f, P = br[c0];
        #pragma unroll
        for (int e = 0; e < EE; ++e) {
            c_r += bdo[e] * wr[e];
            P   += s_v[e] * wr[e];        // P_{-1} = tv0@Wr + br
        }

        float* outb = out + (size_t)b * PRED * CC + c0;

        for (int c = 0; c <= NCH; ++c) {
            if (c > 0) {
                const float* ring = &s_u[(c - 1) & 1][0][0];
                const int n0 = (c - 1) * CH;
                for (int i = 0; i < CH; ++i) {
                    float a0 = c_r, a1 = 0.f, a2 = 0.f, a3 = 0.f;
                    const float4* u4 = (const float4*)(ring + i * HH);
                    #pragma unroll
                    for (int k = 0; k < HH / 4; ++k) {
                        float4 q = u4[k];
                        a0 += q.x * m_r[4 * k    ];
                        a1 += q.y * m_r[4 * k + 1];
                        a2 += q.z * m_r[4 * k + 2];
                        a3 += q.w * m_r[4 * k + 3];
                    }
                    P += (a0 + a1) + (a2 + a3);
                    outb[(size_t)(n0 + i) * CC] = P;
                }
            }
            __syncthreads();
        }
    } else {
        for (int c = 0; c <= NCH; ++c) __syncthreads();
    }
}

extern "C" void kernel_launch(void* const* d_in, const int* in_sizes, int n_in,
                              void* d_out, int out_size, void* d_ws, size_t ws_size,
                              hipStream_t stream)
{
    const float* x    = (const float*)d_in[0];
    const float* WeT  = (const float*)d_in[1];
    const float* beT  = (const float*)d_in[2];
    const float* WeW  = (const float*)d_in[3];
    const float* beW  = (const float*)d_in[4];
    const float* WeD  = (const float*)d_in[5];
    const float* beD  = (const float*)d_in[6];
    const float* WeR  = (const float*)d_in[7];
    const float* beR  = (const float*)d_in[8];
    const float* Wdin = (const float*)d_in[9];
    const float* bdin = (const float*)d_in[10];
    const float* Wdg  = (const float*)d_in[11];
    const float* bdg  = (const float*)d_in[12];
    const float* Wdo  = (const float*)d_in[13];
    const float* bdo  = (const float*)d_in[14];
    const float* Wr   = (const float*)d_in[15];
    const float* br   = (const float*)d_in[16];

    fused_kernel<<<BB, 256, 0, stream>>>(x, WeT, beT, WeW, beW, WeD, beD,
                                         WeR, beR, Wdin, bdin, Wdg, bdg,
                                         Wdo, bdo, Wr, br, (float*)d_out);
}

// Round 8
// 397.981 us; speedup vs baseline: 1.0922x; 1.0274x over previous
//
#include <hip/hip_runtime.h>

typedef float v2f __attribute__((ext_vector_type(2)));

#define T_LEN 2048
#define BB    128
#define CC    128
#define EE    32
#define HH    64
#define PRED  336
#define CH    16          // steps per ring chunk
#define NCH   21          // 21*16 = 336

#define PADT(t) ((t) + ((t) >> 6))   // encode GEMV reads stride-64 -> +1/64 pad

__device__ __forceinline__ v2f mk2(float a, float b) { v2f t; t.x = a; t.y = b; return t; }
__device__ __forceinline__ float rl(float v, int j) {
    return __int_as_float(__builtin_amdgcn_readlane(__float_as_int(v), j));
}

// ---------------------------------------------------------------------------
// ONE kernel, one block (256 thr = 4 waves) per batch element.
//
// Prologue: channel-0 extract, 7-tap MA, 4 encoder tanh-GEMVs -> s_v[32].
// Then ALL 256 threads cooperatively build the u-space constant matrices
// into LDS (runtime loops are fine: destination is LDS, not registers):
//   s_Mag[k][h] = (W_o@W_in, W_o@W_g)[k][h]    s_Mr[k][c] = (W_o@Wr)[k][c]
// Each wave then LOADS its columns into registers with a flat fully-unrolled
// constant-offset loop — the R4-proven pattern that stays register-resident
// (computing M directly into register arrays spilled to scratch in R5-R7:
//  VGPR_Count 80/108 vs the >=128 needed; that was the whole regression).
//
// Scan (u-space linear recurrence; logmap0(expmap0(v)) == v):
//   wave 0: u_h = silu(A_h)*sigm(G_h);  AG += u@M_ag + c_ag via v_readlane
//           (register crossbar, zero LDS/zero waitcnt on the serial chain);
//           u posted to the LDS ring (fire-and-forget).
//   waves 1,2: P_c += u@M_r[:,c] + c_r; store P (= pred_n). Double-buffered
//           ring, one barrier per 16 steps.  wave 3: barrier companion.
// ---------------------------------------------------------------------------
__global__ __launch_bounds__(256, 1) void fused_kernel(
    const float* __restrict__ x,
    const float* __restrict__ WeT,  const float* __restrict__ beT,
    const float* __restrict__ WeW,  const float* __restrict__ beW,
    const float* __restrict__ WeD,  const float* __restrict__ beD,
    const float* __restrict__ WeR,  const float* __restrict__ beR,
    const float* __restrict__ Wdin, const float* __restrict__ bdin,
    const float* __restrict__ Wdg,  const float* __restrict__ bdg,
    const float* __restrict__ Wdo,  const float* __restrict__ bdo,
    const float* __restrict__ Wr,   const float* __restrict__ br,
    float* __restrict__ out)
{
    __shared__ __align__(16) float s_x   [T_LEN + 6];
    __shared__ __align__(16) float s_tr  [T_LEN + 32];
    __shared__ __align__(16) float s_rs  [T_LEN + 32];
    __shared__ __align__(16) float s_part[4][32][32];
    __shared__ __align__(16) float s_red [4][32];
    __shared__ __align__(16) float s_v   [EE];
    __shared__ __align__(16) v2f   s_Mag [HH * HH];      // 32 KB
    __shared__ __align__(16) float s_Mr  [HH * CC];      // 32 KB
    __shared__ __align__(16) float s_u   [2][CH][HH];    //  8 KB ring

    const int tid  = threadIdx.x;
    const int wid  = tid >> 6;
    const int lane = tid & 63;
    const int b    = blockIdx.x;
    const float* xb = x + (size_t)b * T_LEN * CC;

    // ---- channel-0 with halo, edge-clamped
    for (int i = tid; i < T_LEN + 6; i += 256) {
        int t = i - 3;
        t = t < 0 ? 0 : (t > T_LEN - 1 ? T_LEN - 1 : t);
        s_x[i] = xb[(size_t)t * CC];
    }
    __syncthreads();

    // ---- 7-tap moving average (s_x index t+3 == global t)
    for (int t = tid; t < T_LEN; t += 256) {
        float s = 0.f;
        #pragma unroll
        for (int j = 0; j < 7; ++j) s += s_x[t + j];
        float tm = s * (1.0f / 7.0f);
        s_tr[PADT(t)] = tm;
        s_rs[PADT(t)] = s_x[t + 3] - tm;
    }
    __syncthreads();

    // ---- 4 encoder GEMV partials: thread = (e-quad eq, t-group tg of 32)
    {
        const int eq = tid & 7, tg = tid >> 3;
        float4 aT = {0,0,0,0}, aW = aT, aD = aT, aR = aT;
        const float4* WT4 = (const float4*)WeT;
        const float4* WW4 = (const float4*)WeW;
        const float4* WD4 = (const float4*)WeD;
        const float4* WR4 = (const float4*)WeR;
        #pragma unroll 4
        for (int j = 0; j < 64; ++j) {
            int t  = tg * 64 + j;
            int wi = t * 8 + eq;
            float trv = s_tr[PADT(t)], rsv = s_rs[PADT(t)];
            float4 w;
            w = WT4[wi]; aT.x += trv*w.x; aT.y += trv*w.y; aT.z += trv*w.z; aT.w += trv*w.w;
            w = WW4[wi]; aW.x += rsv*w.x; aW.y += rsv*w.y; aW.z += rsv*w.z; aW.w += rsv*w.w;
            w = WD4[wi]; aD.x += rsv*w.x; aD.y += rsv*w.y; aD.z += rsv*w.z; aD.w += rsv*w.w;
            w = WR4[wi]; aR.x += rsv*w.x; aR.y += rsv*w.y; aR.z += rsv*w.z; aR.w += rsv*w.w;
        }
        ((float4*)&s_part[0][tg][0])[eq] = aT;
        ((float4*)&s_part[1][tg][0])[eq] = aW;
        ((float4*)&s_part[2][tg][0])[eq] = aD;
        ((float4*)&s_part[3][tg][0])[eq] = aR;
    }
    __syncthreads();

    if (tid < 128) {
        const int m = tid >> 5, e = tid & 31;
        float s = 0.f;
        #pragma unroll
        for (int g = 0; g < 32; ++g) s += s_part[m][g][e];
        s_red[m][e] = s;
    }
    __syncthreads();

    if (tid < EE) {
        s_v[tid] = tanhf(s_red[0][tid] + beT[tid])
                 + tanhf(s_red[1][tid] + beW[tid])
                 + tanhf(s_red[2][tid] + beD[tid])
                 + tanhf(s_red[3][tid] + beR[tid]);
    }

    // ---- cooperative M-build into LDS (no barrier needed before: reads
    //      only global weights, writes fresh LDS regions)
    {
        const int h = tid & 63, kg = tid >> 6;          // kg 0..3
        for (int kk = 0; kk < 16; ++kk) {
            int k = kg * 16 + kk;
            float mi = 0.f, mg = 0.f;
            for (int e = 0; e < EE; ++e) {
                float wo = Wdo[k * EE + e];
                mi += wo * Wdin[e * HH + h];
                mg += wo * Wdg [e * HH + h];
            }
            s_Mag[k * HH + h] = mk2(mi, mg);
        }
        const int c = tid & 127, kg2 = tid >> 7;        // kg2 0..1
        for (int kk = 0; kk < 32; ++kk) {
            int k = kg2 * 32 + kk;
            float m = 0.f;
            for (int e = 0; e < EE; ++e) m += Wdo[k * EE + e] * Wr[e * CC + c];
            s_Mr[k * CC + c] = m;
        }
    }
    __syncthreads();

    if (wid == 0) {
        // ================= producer: A,G state for h = lane =================
        // flat unrolled constant-offset LDS load -> stays in VGPRs (R4 pattern)
        v2f m_ag[HH];
        #pragma unroll
        for (int k = 0; k < HH; ++k) m_ag[k] = s_Mag[k * HH + lane];

        v2f c_ag = mk2(0.f, 0.f);
        v2f ag   = mk2(bdin[lane], bdg[lane]);
        #pragma unroll
        for (int e = 0; e < EE; ++e) {
            v2f w = mk2(Wdin[e * HH + lane], Wdg[e * HH + lane]);
            c_ag += bdo[e] * w;
            ag   += s_v[e] * w;
        }

        for (int c = 0; c <= NCH; ++c) {
            if (c < NCH) {
                float* ring = &s_u[c & 1][0][0];
                for (int i = 0; i < CH; ++i) {
                    float a = ag.x, g = ag.y;
                    float u = a * __builtin_amdgcn_rcpf(
                        (1.f + __expf(-a)) * (1.f + __expf(-g)));
                    ring[i * HH + lane] = u;      // posted; off the serial path

                    v2f acc0 = c_ag, acc1 = mk2(0.f, 0.f),
                        acc2 = acc1, acc3 = acc1;
                    #pragma unroll
                    for (int j = 0; j < HH; j += 4) {
                        acc0 += rl(u, j    ) * m_ag[j    ];
                        acc1 += rl(u, j + 1) * m_ag[j + 1];
                        acc2 += rl(u, j + 2) * m_ag[j + 2];
                        acc3 += rl(u, j + 3) * m_ag[j + 3];
                    }
                    ag += (acc0 + acc1) + (acc2 + acc3);
                }
            }
            __syncthreads();
        }
    } else if (wid <= 2) {
        // ============ consumer: P state (pred) for channel c0 ===============
        const int c0 = (wid - 1) * 64 + lane;
        float m_r[HH];
        #pragma unroll
        for (int k = 0; k < HH; ++k) m_r[k] = s_Mr[k * CC + c0];

        float c_r = 0.f, P = br[c0];
        #pragma unroll
        for (int e = 0; e < EE; ++e) {
            float w = Wr[e * CC + c0];
            c_r += bdo[e] * w;
            P   += s_v[e] * w;            // P_{-1} = tv0@Wr + br
        }

        float* outb = out + (size_t)b * PRED * CC + c0;

        for (int c = 0; c <= NCH; ++c) {
            if (c > 0) {
                const float* ring = &s_u[(c - 1) & 1][0][0];
                const int n0 = (c - 1) * CH;
                for (int i = 0; i < CH; ++i) {
                    float a0 = c_r, a1 = 0.f, a2 = 0.f, a3 = 0.f;
                    const float4* u4 = (const float4*)(ring + i * HH);
                    #pragma unroll
                    for (int k = 0; k < HH / 4; ++k) {
                        float4 q = u4[k];
                        a0 += q.x * m_r[4 * k    ];
                        a1 += q.y * m_r[4 * k + 1];
                        a2 += q.z * m_r[4 * k + 2];
                        a3 += q.w * m_r[4 * k + 3];
                    }
                    P += (a0 + a1) + (a2 + a3);
                    outb[(size_t)(n0 + i) * CC] = P;
                }
            }
            __syncthreads();
        }
    } else {
        for (int c = 0; c <= NCH; ++c) __syncthreads();
    }
}

extern "C" void kernel_launch(void* const* d_in, const int* in_sizes, int n_in,
                              void* d_out, int out_size, void* d_ws, size_t ws_size,
                              hipStream_t stream)
{
    const float* x    = (const float*)d_in[0];
    const float* WeT  = (const float*)d_in[1];
    const float* beT  = (const float*)d_in[2];
    const float* WeW  = (const float*)d_in[3];
    const float* beW  = (const float*)d_in[4];
    const float* WeD  = (const float*)d_in[5];
    const float* beD  = (const float*)d_in[6];
    const float* WeR  = (const float*)d_in[7];
    const float* beR  = (const float*)d_in[8];
    const float* Wdin = (const float*)d_in[9];
    const float* bdin = (const float*)d_in[10];
    const float* Wdg  = (const float*)d_in[11];
    const float* bdg  = (const float*)d_in[12];
    const float* Wdo  = (const float*)d_in[13];
    const float* bdo  = (const float*)d_in[14];
    const float* Wr   = (const float*)d_in[15];
    const float* br   = (const float*)d_in[16];

    fused_kernel<<<BB, 256, 0, stream>>>(x, WeT, beT, WeW, beW, WeD, beD,
                                         WeR, beR, Wdin, bdin, Wdg, bdg,
                                         Wdo, bdo, Wr, br, (float*)d_out);
}